// Round 6
// baseline (2234.000 us; speedup 1.0000x reference)
//
#include <hip/hip_runtime.h>
#include <cstddef>

#define T_ 1024
#define B_ 128
#define F_ 243
#define H_ 20
#define G_ 60   // 3*H
#define R_ 512  // B*POOL
#define P_ 8    // xg prefetch depth in k2 (also the e-store shift)
#define FP_ 256 // padded F for Wt (f-major transposed W_ih)

__device__ __forceinline__ float rdlane(float v, int l) {
  return __int_as_float(__builtin_amdgcn_readlane(__float_as_int(v), l));
}

// ---------------- K0: transpose W_ih -> Wt[256][60] (f-major, zero-padded) ----------------
__global__ __launch_bounds__(256) void k0_wt(
    const float* __restrict__ W_ih, float* __restrict__ Wt)
{
  const int i = blockIdx.x * 256 + threadIdx.x;   // 60 blocks -> 15360 = FP_*G_
  if (i < FP_ * G_) {
    const int f = i / G_, g = i - f * G_;
    Wt[(size_t)f * G_ + g] = (f < F_) ? W_ih[(size_t)g * F_ + f] : 0.f;
  }
}

// ---------------- K1: fused max-pool(4) + GEMM  xg = pool(feats) @ W_ih^T + b_ih ----------
// Block = (b, 64 consecutive t). 8 f-chunks of 32. BOTH operands double-
// buffered in LDS (As 2x8KB + Ws 2x7.5KB = 31KB -> 5 blocks/CU): round 5
// proved W-from-global thrashes L2 under feats streaming (FETCH 1.65GB).
// Thread tile 4 rows x 4 gates. A swizzle (validated round 5, 0 conflicts):
// element (row,f) stored at quad (f>>2)^((row>>2)&3).
// One barrier per chunk; stage of chunk c+1 issued before compute of c.
__global__ __launch_bounds__(256, 5) void k1_fused(
    const float* __restrict__ feats, const float* __restrict__ Wt,
    const float* __restrict__ b_ih, float* __restrict__ h_seq,
    float* __restrict__ xg)
{
  __shared__ __align__(16) float As[2][64 * 32];   // 2 x 8 KB
  __shared__ __align__(16) float Ws[2][32 * 60];   // 2 x 7.5 KB
  const int bid = blockIdx.x;
  const int b = bid >> 4;                  // consecutive bids share b (round-4 style)
  const int t0 = (bid & 15) << 6;
  const int tid = threadIdx.x;
  const int rg = tid >> 4;                 // 0..15 -> rows rg*4..rg*4+3
  const int gcol = tid & 15;               // 0..15 -> gates gcol*4..+3
  const int gc4 = (gcol < 15) ? gcol * 4 : 56;   // clamp col 15 (dup of 14)

  // staging coords: 32 cols x 8 row-sets per 256 threads
  const int srow0 = tid >> 5;              // 0..7
  const int scol = tid & 31;

  float acc[4][4];
  #pragma unroll
  for (int i = 0; i < 4; ++i)
    #pragma unroll
    for (int j = 0; j < 4; ++j) acc[i][j] = 0.f;

#define STAGE(BUF, C, GUARD)                                                 \
  {                                                                          \
    const int FC = (C) * 32;                                                 \
    _Pragma("unroll")                                                        \
    for (int k = 0; k < 8; ++k) {                                            \
      const int row = srow0 + 8 * k;                                         \
      float v = 0.f;                                                         \
      if (!(GUARD) || (FC + scol < F_)) {                                    \
        const float* p = feats +                                             \
            ((size_t)(t0 + row) * R_ + (size_t)b * 4) * F_ + FC + scol;      \
        v = fmaxf(fmaxf(p[0], p[F_]), fmaxf(p[2 * F_], p[3 * F_]));          \
        h_seq[((size_t)b * T_ + t0 + row) * F_ + FC + scol] = v;             \
      }                                                                      \
      As[BUF][(row << 5) + ((((scol >> 2) ^ ((row >> 2) & 3)) << 2) |        \
              (scol & 3))] = v;                                              \
    }                                                                        \
    _Pragma("unroll")                                                        \
    for (int j = tid; j < 32 * 60; j += 256)                                 \
      Ws[BUF][j] = Wt[(size_t)(FC) * 60 + j];                                \
  }

#define COMPUTE(BUF)                                                         \
  {                                                                          \
    _Pragma("unroll")                                                        \
    for (int fj = 0; fj < 8; ++fj) {                                         \
      const float* wp = &Ws[BUF][(fj * 4) * 60 + gc4];                       \
      const float4 w0 = *(const float4*)(wp);                                \
      const float4 w1 = *(const float4*)(wp + 60);                           \
      const float4 w2 = *(const float4*)(wp + 120);                          \
      const float4 w3 = *(const float4*)(wp + 180);                          \
      _Pragma("unroll")                                                      \
      for (int i = 0; i < 4; ++i) {                                          \
        const int row = rg * 4 + i;                                          \
        const float4 a4 =                                                    \
            *(const float4*)&As[BUF][(row << 5) + ((fj ^ (rg & 3)) << 2)];   \
        acc[i][0] = fmaf(a4.x, w0.x, fmaf(a4.y, w1.x, fmaf(a4.z, w2.x, fmaf(a4.w, w3.x, acc[i][0])))); \
        acc[i][1] = fmaf(a4.x, w0.y, fmaf(a4.y, w1.y, fmaf(a4.z, w2.y, fmaf(a4.w, w3.y, acc[i][1])))); \
        acc[i][2] = fmaf(a4.x, w0.z, fmaf(a4.y, w1.z, fmaf(a4.z, w2.z, fmaf(a4.w, w3.z, acc[i][2])))); \
        acc[i][3] = fmaf(a4.x, w0.w, fmaf(a4.y, w1.w, fmaf(a4.z, w2.w, fmaf(a4.w, w3.w, acc[i][3])))); \
      }                                                                      \
    }                                                                        \
  }

  STAGE(0, 0, 0)
  __syncthreads();
  STAGE(1, 1, 0) COMPUTE(0) __syncthreads();
  STAGE(0, 2, 0) COMPUTE(1) __syncthreads();
  STAGE(1, 3, 0) COMPUTE(0) __syncthreads();
  STAGE(0, 4, 0) COMPUTE(1) __syncthreads();
  STAGE(1, 5, 0) COMPUTE(0) __syncthreads();
  STAGE(0, 6, 0) COMPUTE(1) __syncthreads();
  STAGE(1, 7, 1) COMPUTE(0) __syncthreads();
  COMPUTE(1)
#undef STAGE
#undef COMPUTE

  if (gcol < 15) {
    const float4 bi4 = *(const float4*)&b_ih[gc4];
    #pragma unroll
    for (int i = 0; i < 4; ++i) {
      const int row = rg * 4 + i;
      float4 o;
      o.x = acc[i][0] + bi4.x;  o.y = acc[i][1] + bi4.y;
      o.z = acc[i][2] + bi4.z;  o.w = acc[i][3] + bi4.w;
      *(float4*)&xg[((size_t)b * T_ + t0 + row) * G_ + gc4] = o;
    }
  }
}

// ---------------- K2: recurrence only, zero cross-lane DS ops ----------------
// One wave per batch row. Lane j<20 owns the gate triple (r_j,z_j,n_j); the
// shared e vector lives in SGPR pairs via v_readlane; dots run as float2 math
// so the compiler can emit v_pk_fma_f32. e(t) goes into THIS block's own xg
// slab at packed offset (t-8)*20 (read >=8 steps earlier); t<8 -> ehead.
// NOTE: xg / e_store intentionally NOT __restrict__ (they alias).
__global__ __launch_bounds__(64) void k2_recur(
    const float* __restrict__ e0, const float* __restrict__ W_hh,
    const float* __restrict__ b_hh, const float* xg,
    float* e_store, float* __restrict__ ehead)
{
  const int b = blockIdx.x;
  const int lane = threadIdx.x;
  const bool own = lane < H_;
  const int j0 = own ? lane : 0;

  float2 wr2[10], wz2[10], wn2[10];
  #pragma unroll
  for (int k = 0; k < 10; ++k) {
    wr2[k] = *(const float2*)&W_hh[j0 * H_ + 2 * k];
    wz2[k] = *(const float2*)&W_hh[(j0 + 20) * H_ + 2 * k];
    wn2[k] = *(const float2*)&W_hh[(j0 + 40) * H_ + 2 * k];
  }
  const float bhr = b_hh[j0], bhz = b_hh[j0 + 20], bhn = b_hh[j0 + 40];

  float e_own = e0[b * H_ + j0];
  float2 es2[10];
  #pragma unroll
  for (int k = 0; k < 10; ++k) {
    es2[k].x = rdlane(e_own, 2 * k);
    es2[k].y = rdlane(e_own, 2 * k + 1);
  }

  const float* xgb = xg + (size_t)b * T_ * G_;
  float* xslab = e_store + (size_t)b * T_ * G_;   // packed e at (t-8)*20
  float* ehb = ehead + b * (P_ * H_);

  float xr[P_], xz[P_], xn[P_];
  #pragma unroll
  for (int j = 0; j < P_; ++j) {
    xr[j] = xgb[(size_t)j * G_ + j0];
    xz[j] = xgb[(size_t)j * G_ + j0 + 20];
    xn[j] = xgb[(size_t)j * G_ + j0 + 40];
  }

#define STEP(j, RELOAD)                                                    \
  {                                                                        \
    const int t = t0 + (j);                                                \
    const float xrv = xr[j], xzv = xz[j], xnv = xn[j];                     \
    if (RELOAD) {                                                          \
      const float* xp = xgb + (size_t)(t + P_) * G_;                       \
      xr[j] = xp[j0]; xz[j] = xp[j0 + 20]; xn[j] = xp[j0 + 40];            \
    }                                                                      \
    float2 r2 = make_float2(bhr, 0.f);                                     \
    float2 z2 = make_float2(bhz, 0.f);                                     \
    float2 n2 = make_float2(bhn, 0.f);                                     \
    _Pragma("unroll")                                                      \
    for (int k = 0; k < 10; ++k) {                                         \
      r2 = wr2[k] * es2[k] + r2;                                           \
      z2 = wz2[k] * es2[k] + z2;                                           \
      n2 = wn2[k] * es2[k] + n2;                                           \
    }                                                                      \
    const float hr = r2.x + r2.y, hz = z2.x + z2.y, hn = n2.x + n2.y;      \
    const float rg = 1.f / (1.f + __expf(-(xrv + hr)));                    \
    const float zg = 1.f / (1.f + __expf(-(xzv + hz)));                    \
    const float aa = xnv + rg * hn;                                        \
    const float ng = 1.f - 2.f / (__expf(2.f * aa) + 1.f);                 \
    const float enew = (1.f - zg) * ng + zg * e_own;                       \
    if (own) {                                                             \
      float* dst = (t >= P_) ? (xslab + (size_t)(t - P_) * H_ + lane)      \
                             : (ehb + t * H_ + lane);                      \
      *dst = enew;                                                         \
    }                                                                      \
    e_own = enew;                                                          \
    _Pragma("unroll")                                                      \
    for (int k = 0; k < 10; ++k) {                                         \
      es2[k].x = rdlane(enew, 2 * k);                                      \
      es2[k].y = rdlane(enew, 2 * k + 1);                                  \
    }                                                                      \
  }

  for (int t0 = 0; t0 < T_ - P_; t0 += P_) {
    STEP(0, true) STEP(1, true) STEP(2, true) STEP(3, true)
    STEP(4, true) STEP(5, true) STEP(6, true) STEP(7, true)
  }
  {
    const int t0 = T_ - P_;
    STEP(0, false) STEP(1, false) STEP(2, false) STEP(3, false)
    STEP(4, false) STEP(5, false) STEP(6, false) STEP(7, false)
  }
#undef STEP
}

// ---------------- K4: decoder + squared-error ----------------
#define K4_ROWS 128
__global__ __launch_bounds__(256) void k4_decode(
    const float* __restrict__ W_dec, const float* __restrict__ b_dec,
    const float* __restrict__ h_seq, const float* __restrict__ e_store,
    const float* __restrict__ ehead, float* __restrict__ partials)
{
  __shared__ float elds[K4_ROWS * H_];   // 10 KB
  __shared__ float red[4];
  const int tid = threadIdx.x;
  const int f = tid;
  const bool act = f < F_;
  const int lane = tid & 63, wave = tid >> 6;
  const size_t r0 = (size_t)blockIdx.x * K4_ROWS;
  const int b = (int)(r0 >> 10);
  const int t0 = (int)(r0 & (T_ - 1));
  const float* xslab = e_store + (size_t)b * T_ * G_;
  const float* ehb = ehead + b * (P_ * H_);

  for (int i = tid; i < K4_ROWS * H_; i += 256) {
    const int trow = i / H_;
    const int c = i - trow * H_;
    const int t = t0 + trow;
    elds[i] = (t >= P_) ? xslab[(size_t)(t - P_) * H_ + c] : ehb[t * H_ + c];
  }

  float wd[H_];
  float bd = 0.f;
  if (act) {
    #pragma unroll
    for (int k = 0; k < H_; ++k) wd[k] = W_dec[f * H_ + k];
    bd = b_dec[f];
  }
  __syncthreads();

  float acc = 0.f;
  #pragma unroll 2
  for (int i = 0; i < K4_ROWS; ++i) {
    const float2* ep = (const float2*)&elds[i * H_];
    float d = bd;
    #pragma unroll
    for (int k = 0; k < 10; ++k) {
      const float2 e2 = ep[k];
      d = fmaf(wd[2 * k], e2.x, fmaf(wd[2 * k + 1], e2.y, d));
    }
    const float fo = fmaxf(d, 0.f);
    if (act) {
      const float h = h_seq[(r0 + i) * F_ + f];
      const float df = fo - h;
      acc = fmaf(df, df, acc);
    }
  }

  #pragma unroll
  for (int m = 32; m >= 1; m >>= 1) acc += __shfl_xor(acc, m);
  if (lane == 0) red[wave] = acc;
  __syncthreads();
  if (tid == 0) partials[blockIdx.x] = red[0] + red[1] + red[2] + red[3];
}

// ---------------- K3: final deterministic reduction over 1024 partials ----------------
__global__ __launch_bounds__(64) void k3_reduce(
    const float* __restrict__ partials, float* __restrict__ out)
{
  const int lane = threadIdx.x;
  float a = 0.f;
  #pragma unroll
  for (int i = 0; i < 16; ++i) a += partials[i * 64 + lane];
  #pragma unroll
  for (int m = 32; m >= 1; m >>= 1) a += __shfl_xor(a, m);
  if (lane == 0) out[0] = a * (float)(1.0 / ((double)T_ * B_ * F_));
}

extern "C" void kernel_launch(void* const* d_in, const int* in_sizes, int n_in,
                              void* d_out, int out_size, void* d_ws, size_t ws_size,
                              hipStream_t stream) {
  const float* feats = (const float*)d_in[0];
  const float* e0    = (const float*)d_in[1];
  const float* W_ih  = (const float*)d_in[2];
  const float* W_hh  = (const float*)d_in[3];
  const float* b_ih  = (const float*)d_in[4];
  const float* b_hh  = (const float*)d_in[5];
  const float* W_dec = (const float*)d_in[6];
  const float* b_dec = (const float*)d_in[7];
  float* out = (float*)d_out;

  float* ws = (float*)d_ws;
  float* h_seq    = ws;                                    // B*T*F floats (b-major)
  float* xgates   = ws + (size_t)T_ * B_ * F_;             // B*T*G floats (b-major)
  float* partials = xgates + (size_t)T_ * B_ * G_;         // 1024 floats
  float* ehead    = partials + 1024;                       // B*8*H floats (e for t<8)
  float* Wt       = ehead + B_ * P_ * H_;                  // FP_*G_ floats

  hipLaunchKernelGGL(k0_wt, dim3(60), dim3(256), 0, stream, W_ih, Wt);
  hipLaunchKernelGGL(k1_fused, dim3(B_ * 16), dim3(256), 0, stream,
                     feats, Wt, b_ih, h_seq, xgates);
  hipLaunchKernelGGL(k2_recur, dim3(B_), dim3(64), 0, stream,
                     e0, W_hh, b_hh, xgates, xgates, ehead);
  hipLaunchKernelGGL(k4_decode, dim3((T_ * B_) / K4_ROWS), dim3(256), 0, stream,
                     W_dec, b_dec, h_seq, xgates, ehead, partials);
  hipLaunchKernelGGL(k3_reduce, dim3(1), dim3(64), 0, stream,
                     partials, out);
}

// Round 7
// 1594.535 us; speedup vs baseline: 1.4010x; 1.4010x over previous
//
#include <hip/hip_runtime.h>
#include <cstddef>

#define T_ 1024
#define B_ 128
#define F_ 243
#define H_ 20
#define G_ 60   // 3*H
#define R_ 512  // B*POOL
#define P_ 8    // xg prefetch depth in k2 (also the e-store shift)
#define FP_ 256 // padded F for Wt (f-major transposed W_ih)

__device__ __forceinline__ float rdlane(float v, int l) {
  return __int_as_float(__builtin_amdgcn_readlane(__float_as_int(v), l));
}

// ---------------- K0: transpose W_ih -> Wt[256][60] (f-major, zero-padded) ----------------
__global__ __launch_bounds__(256) void k0_wt(
    const float* __restrict__ W_ih, float* __restrict__ Wt)
{
  const int i = blockIdx.x * 256 + threadIdx.x;   // 60 blocks -> 15360 = FP_*G_
  if (i < FP_ * G_) {
    const int f = i / G_, g = i - f * G_;
    Wt[(size_t)f * G_ + g] = (f < F_) ? W_ih[(size_t)g * F_ + f] : 0.f;
  }
}

// ---------------- K1a: pure streaming max-pool(4): feats -> h_seq (b-major) --------------
// Fully contiguous 972-B reads and writes, 32 independent loads per thread,
// no LDS, no barriers. Consecutive bids share the t-window (good DRAM locality
// on feats); each b writes a contiguous h_seq stream.
__global__ __launch_bounds__(256) void k1a_pool(
    const float* __restrict__ feats, float* __restrict__ h_seq)
{
  const int bid = blockIdx.x;           // 16384 = 1024 t x 16 b-groups
  const int t = bid & (T_ - 1);
  const int b0 = (bid >> 10) << 3;      // 8 batch rows per block
  const int col = threadIdx.x;
  if (col < F_) {
    #pragma unroll
    for (int bb = 0; bb < 8; ++bb) {
      const float* p =
          feats + ((size_t)t * R_ + (size_t)(b0 + bb) * 4) * F_ + col;
      const float v =
          fmaxf(fmaxf(p[0], p[F_]), fmaxf(p[2 * F_], p[3 * F_]));
      h_seq[((size_t)(b0 + bb) * T_ + t) * F_ + col] = v;
    }
  }
}

// ---------------- K1b: GEMM  xg = h_seq @ W_ih^T + b_ih  (reads pooled data) -------------
// Block = (b, 128 consecutive t) -> A slab is 124 KB CONTIGUOUS in h_seq.
// 4 f-chunks of 64. As[128x64] + Ws[64x60] single-buffered in LDS (47 KB,
// 3 blocks/CU); TRUE async staging: chunk c+1's A/W loads are issued into
// pf[32]/wreg[15] registers BEFORE COMPUTE(c) and only consumed (ds_write) at
// the next chunk's stage phase -> HBM latency hides under 2048 FMAs (T14).
// A swizzle (validated, 0 conflicts): quad (col>>2)^(row>>3); compute reads
// quad (fj^rg)&15 so the 4 row-groups of a wave hit disjoint bank quads.
__global__ __launch_bounds__(256, 3) void k1b_gemm(
    const float* __restrict__ h_seq, const float* __restrict__ Wt,
    const float* __restrict__ b_ih, float* __restrict__ xg)
{
  __shared__ __align__(16) float As[128 * 64];   // 32 KB
  __shared__ __align__(16) float Ws[64 * 60];    // 15 KB
  const int bid = blockIdx.x;
  const int b = bid >> 3;
  const int t0 = (bid & 7) << 7;
  const int tid = threadIdx.x;
  const int rg = tid >> 4;                 // 0..15 -> rows rg*8..rg*8+7
  const int gcol = tid & 15;               // 0..15 -> gates gcol*4..+3
  const int gc4 = (gcol < 15) ? gcol * 4 : 56;   // clamp col 15 (dup of 14)

  const int rowbase = tid >> 6;            // 0..3 (stage rows rowbase+4e)
  const int scol = tid & 63;               // stage col within chunk
  const float* hsb = h_seq + ((size_t)b * T_ + t0) * F_;

  float pf[32];
  float wreg[15];
  float acc[8][4];
  #pragma unroll
  for (int i = 0; i < 8; ++i)
    #pragma unroll
    for (int j = 0; j < 4; ++j) acc[i][j] = 0.f;

#define PF(C, GUARD)                                                         \
  {                                                                          \
    const int FC = (C) * 64;                                                 \
    _Pragma("unroll")                                                        \
    for (int e = 0; e < 32; ++e) {                                           \
      const int row = rowbase + 4 * e;                                       \
      pf[e] = (!(GUARD) || (FC + scol < F_))                                 \
                  ? hsb[(size_t)row * F_ + FC + scol] : 0.f;                 \
    }                                                                        \
    _Pragma("unroll")                                                        \
    for (int k = 0; k < 15; ++k)                                             \
      wreg[k] = Wt[(size_t)FC * G_ + tid + 256 * k];                         \
  }

#define WSTAGE()                                                             \
  {                                                                          \
    _Pragma("unroll")                                                        \
    for (int e = 0; e < 32; ++e) {                                           \
      const int row = rowbase + 4 * e;                                       \
      As[(row << 6) + ((((scol >> 2) ^ (row >> 3)) & 15) << 2) +             \
         (scol & 3)] = pf[e];                                                \
    }                                                                        \
    _Pragma("unroll")                                                        \
    for (int k = 0; k < 15; ++k) Ws[tid + 256 * k] = wreg[k];                \
  }

#define COMPUTE()                                                            \
  {                                                                          \
    _Pragma("unroll")                                                        \
    for (int fj = 0; fj < 16; ++fj) {                                        \
      const float* wp = &Ws[(fj * 4) * 60 + gc4];                            \
      const float4 w0 = *(const float4*)(wp);                                \
      const float4 w1 = *(const float4*)(wp + 60);                           \
      const float4 w2 = *(const float4*)(wp + 120);                          \
      const float4 w3 = *(const float4*)(wp + 180);                          \
      _Pragma("unroll")                                                      \
      for (int i = 0; i < 8; ++i) {                                          \
        const int row = (rg << 3) + i;                                       \
        const float4 a4 =                                                    \
            *(const float4*)&As[(row << 6) + (((fj ^ rg) & 15) << 2)];       \
        acc[i][0] = fmaf(a4.x, w0.x, fmaf(a4.y, w1.x, fmaf(a4.z, w2.x, fmaf(a4.w, w3.x, acc[i][0])))); \
        acc[i][1] = fmaf(a4.x, w0.y, fmaf(a4.y, w1.y, fmaf(a4.z, w2.y, fmaf(a4.w, w3.y, acc[i][1])))); \
        acc[i][2] = fmaf(a4.x, w0.z, fmaf(a4.y, w1.z, fmaf(a4.z, w2.z, fmaf(a4.w, w3.z, acc[i][2])))); \
        acc[i][3] = fmaf(a4.x, w0.w, fmaf(a4.y, w1.w, fmaf(a4.z, w2.w, fmaf(a4.w, w3.w, acc[i][3])))); \
      }                                                                      \
    }                                                                        \
  }

  PF(0, 0)
  __syncthreads();
  WSTAGE()
  __syncthreads();
  PF(1, 0) COMPUTE()
  __syncthreads();
  WSTAGE()
  __syncthreads();
  PF(2, 0) COMPUTE()
  __syncthreads();
  WSTAGE()
  __syncthreads();
  PF(3, 1) COMPUTE()
  __syncthreads();
  WSTAGE()
  __syncthreads();
  COMPUTE()
#undef PF
#undef WSTAGE
#undef COMPUTE

  if (gcol < 15) {
    const float4 bi4 = *(const float4*)&b_ih[gc4];
    #pragma unroll
    for (int i = 0; i < 8; ++i) {
      const int row = (rg << 3) + i;
      float4 o;
      o.x = acc[i][0] + bi4.x;  o.y = acc[i][1] + bi4.y;
      o.z = acc[i][2] + bi4.z;  o.w = acc[i][3] + bi4.w;
      *(float4*)&xg[((size_t)b * T_ + t0 + row) * G_ + gc4] = o;
    }
  }
}

// ---------------- K2: recurrence only, zero cross-lane DS ops ----------------
// One wave per batch row. Lane j<20 owns the gate triple (r_j,z_j,n_j); the
// shared e vector lives in SGPR pairs via v_readlane; dots run as float2 math
// so the compiler can emit v_pk_fma_f32. e(t) goes into THIS block's own xg
// slab at packed offset (t-8)*20 (read >=8 steps earlier); t<8 -> ehead.
// NOTE: xg / e_store intentionally NOT __restrict__ (they alias).
__global__ __launch_bounds__(64) void k2_recur(
    const float* __restrict__ e0, const float* __restrict__ W_hh,
    const float* __restrict__ b_hh, const float* xg,
    float* e_store, float* __restrict__ ehead)
{
  const int b = blockIdx.x;
  const int lane = threadIdx.x;
  const bool own = lane < H_;
  const int j0 = own ? lane : 0;

  float2 wr2[10], wz2[10], wn2[10];
  #pragma unroll
  for (int k = 0; k < 10; ++k) {
    wr2[k] = *(const float2*)&W_hh[j0 * H_ + 2 * k];
    wz2[k] = *(const float2*)&W_hh[(j0 + 20) * H_ + 2 * k];
    wn2[k] = *(const float2*)&W_hh[(j0 + 40) * H_ + 2 * k];
  }
  const float bhr = b_hh[j0], bhz = b_hh[j0 + 20], bhn = b_hh[j0 + 40];

  float e_own = e0[b * H_ + j0];
  float2 es2[10];
  #pragma unroll
  for (int k = 0; k < 10; ++k) {
    es2[k].x = rdlane(e_own, 2 * k);
    es2[k].y = rdlane(e_own, 2 * k + 1);
  }

  const float* xgb = xg + (size_t)b * T_ * G_;
  float* xslab = e_store + (size_t)b * T_ * G_;   // packed e at (t-8)*20
  float* ehb = ehead + b * (P_ * H_);

  float xr[P_], xz[P_], xn[P_];
  #pragma unroll
  for (int j = 0; j < P_; ++j) {
    xr[j] = xgb[(size_t)j * G_ + j0];
    xz[j] = xgb[(size_t)j * G_ + j0 + 20];
    xn[j] = xgb[(size_t)j * G_ + j0 + 40];
  }

#define STEP(j, RELOAD)                                                    \
  {                                                                        \
    const int t = t0 + (j);                                                \
    const float xrv = xr[j], xzv = xz[j], xnv = xn[j];                     \
    if (RELOAD) {                                                          \
      const float* xp = xgb + (size_t)(t + P_) * G_;                       \
      xr[j] = xp[j0]; xz[j] = xp[j0 + 20]; xn[j] = xp[j0 + 40];            \
    }                                                                      \
    float2 r2 = make_float2(bhr, 0.f);                                     \
    float2 z2 = make_float2(bhz, 0.f);                                     \
    float2 n2 = make_float2(bhn, 0.f);                                     \
    _Pragma("unroll")                                                      \
    for (int k = 0; k < 10; ++k) {                                         \
      r2 = wr2[k] * es2[k] + r2;                                           \
      z2 = wz2[k] * es2[k] + z2;                                           \
      n2 = wn2[k] * es2[k] + n2;                                           \
    }                                                                      \
    const float hr = r2.x + r2.y, hz = z2.x + z2.y, hn = n2.x + n2.y;      \
    const float rg = 1.f / (1.f + __expf(-(xrv + hr)));                    \
    const float zg = 1.f / (1.f + __expf(-(xzv + hz)));                    \
    const float aa = xnv + rg * hn;                                        \
    const float ng = 1.f - 2.f / (__expf(2.f * aa) + 1.f);                 \
    const float enew = (1.f - zg) * ng + zg * e_own;                       \
    if (own) {                                                             \
      float* dst = (t >= P_) ? (xslab + (size_t)(t - P_) * H_ + lane)      \
                             : (ehb + t * H_ + lane);                      \
      *dst = enew;                                                         \
    }                                                                      \
    e_own = enew;                                                          \
    _Pragma("unroll")                                                      \
    for (int k = 0; k < 10; ++k) {                                         \
      es2[k].x = rdlane(enew, 2 * k);                                      \
      es2[k].y = rdlane(enew, 2 * k + 1);                                  \
    }                                                                      \
  }

  for (int t0 = 0; t0 < T_ - P_; t0 += P_) {
    STEP(0, true) STEP(1, true) STEP(2, true) STEP(3, true)
    STEP(4, true) STEP(5, true) STEP(6, true) STEP(7, true)
  }
  {
    const int t0 = T_ - P_;
    STEP(0, false) STEP(1, false) STEP(2, false) STEP(3, false)
    STEP(4, false) STEP(5, false) STEP(6, false) STEP(7, false)
  }
#undef STEP
}

// ---------------- K4: decoder + squared-error ----------------
#define K4_ROWS 128
__global__ __launch_bounds__(256) void k4_decode(
    const float* __restrict__ W_dec, const float* __restrict__ b_dec,
    const float* __restrict__ h_seq, const float* __restrict__ e_store,
    const float* __restrict__ ehead, float* __restrict__ partials)
{
  __shared__ float elds[K4_ROWS * H_];   // 10 KB
  __shared__ float red[4];
  const int tid = threadIdx.x;
  const int f = tid;
  const bool act = f < F_;
  const int lane = tid & 63, wave = tid >> 6;
  const size_t r0 = (size_t)blockIdx.x * K4_ROWS;
  const int b = (int)(r0 >> 10);
  const int t0 = (int)(r0 & (T_ - 1));
  const float* xslab = e_store + (size_t)b * T_ * G_;
  const float* ehb = ehead + b * (P_ * H_);

  for (int i = tid; i < K4_ROWS * H_; i += 256) {
    const int trow = i / H_;
    const int c = i - trow * H_;
    const int t = t0 + trow;
    elds[i] = (t >= P_) ? xslab[(size_t)(t - P_) * H_ + c] : ehb[t * H_ + c];
  }

  float wd[H_];
  float bd = 0.f;
  if (act) {
    #pragma unroll
    for (int k = 0; k < H_; ++k) wd[k] = W_dec[f * H_ + k];
    bd = b_dec[f];
  }
  __syncthreads();

  float acc = 0.f;
  #pragma unroll 2
  for (int i = 0; i < K4_ROWS; ++i) {
    const float2* ep = (const float2*)&elds[i * H_];
    float d = bd;
    #pragma unroll
    for (int k = 0; k < 10; ++k) {
      const float2 e2 = ep[k];
      d = fmaf(wd[2 * k], e2.x, fmaf(wd[2 * k + 1], e2.y, d));
    }
    const float fo = fmaxf(d, 0.f);
    if (act) {
      const float h = h_seq[(r0 + i) * F_ + f];
      const float df = fo - h;
      acc = fmaf(df, df, acc);
    }
  }

  #pragma unroll
  for (int m = 32; m >= 1; m >>= 1) acc += __shfl_xor(acc, m);
  if (lane == 0) red[wave] = acc;
  __syncthreads();
  if (tid == 0) partials[blockIdx.x] = red[0] + red[1] + red[2] + red[3];
}

// ---------------- K3: final deterministic reduction over 1024 partials ----------------
__global__ __launch_bounds__(64) void k3_reduce(
    const float* __restrict__ partials, float* __restrict__ out)
{
  const int lane = threadIdx.x;
  float a = 0.f;
  #pragma unroll
  for (int i = 0; i < 16; ++i) a += partials[i * 64 + lane];
  #pragma unroll
  for (int m = 32; m >= 1; m >>= 1) a += __shfl_xor(a, m);
  if (lane == 0) out[0] = a * (float)(1.0 / ((double)T_ * B_ * F_));
}

extern "C" void kernel_launch(void* const* d_in, const int* in_sizes, int n_in,
                              void* d_out, int out_size, void* d_ws, size_t ws_size,
                              hipStream_t stream) {
  const float* feats = (const float*)d_in[0];
  const float* e0    = (const float*)d_in[1];
  const float* W_ih  = (const float*)d_in[2];
  const float* W_hh  = (const float*)d_in[3];
  const float* b_ih  = (const float*)d_in[4];
  const float* b_hh  = (const float*)d_in[5];
  const float* W_dec = (const float*)d_in[6];
  const float* b_dec = (const float*)d_in[7];
  float* out = (float*)d_out;

  float* ws = (float*)d_ws;
  float* h_seq    = ws;                                    // B*T*F floats (b-major)
  float* xgates   = ws + (size_t)T_ * B_ * F_;             // B*T*G floats (b-major)
  float* partials = xgates + (size_t)T_ * B_ * G_;         // 1024 floats
  float* ehead    = partials + 1024;                       // B*8*H floats (e for t<8)
  float* Wt       = ehead + B_ * P_ * H_;                  // FP_*G_ floats

  hipLaunchKernelGGL(k0_wt, dim3(60), dim3(256), 0, stream, W_ih, Wt);
  hipLaunchKernelGGL(k1a_pool, dim3(T_ * (B_ / 8)), dim3(256), 0, stream,
                     feats, h_seq);
  hipLaunchKernelGGL(k1b_gemm, dim3(B_ * 8), dim3(256), 0, stream,
                     h_seq, Wt, b_ih, xgates);
  hipLaunchKernelGGL(k2_recur, dim3(B_), dim3(64), 0, stream,
                     e0, W_hh, b_hh, xgates, xgates, ehead);
  hipLaunchKernelGGL(k4_decode, dim3((T_ * B_) / K4_ROWS), dim3(256), 0, stream,
                     W_dec, b_dec, h_seq, xgates, ehead, partials);
  hipLaunchKernelGGL(k3_reduce, dim3(1), dim3(64), 0, stream,
                     partials, out);
}

// Round 8
// 1589.974 us; speedup vs baseline: 1.4051x; 1.0029x over previous
//
#include <hip/hip_runtime.h>
#include <cstddef>

#define T_ 1024
#define B_ 128
#define F_ 243
#define H_ 20
#define G_ 60   // 3*H
#define R_ 512  // B*POOL
#define P_ 8    // xg prefetch depth in k2 (also the e-store shift)
#define FP_ 256 // padded F for Wt (f-major transposed W_ih)

__device__ __forceinline__ float rdlane(float v, int l) {
  return __int_as_float(__builtin_amdgcn_readlane(__float_as_int(v), l));
}

// ---------------- K0: transpose W_ih -> Wt[256][60] (f-major, zero-padded) ----------------
__global__ __launch_bounds__(256) void k0_wt(
    const float* __restrict__ W_ih, float* __restrict__ Wt)
{
  const int i = blockIdx.x * 256 + threadIdx.x;   // 60 blocks -> 15360 = FP_*G_
  if (i < FP_ * G_) {
    const int f = i / G_, g = i - f * G_;
    Wt[(size_t)f * G_ + g] = (f < F_) ? W_ih[(size_t)g * F_ + f] : 0.f;
  }
}

// ---------------- K1a: pure streaming max-pool(4): feats -> h_seq (b-major) --------------
// Fully contiguous 31-KB reads per block (t-row, 8 b-groups), no LDS, no
// barriers. Validated round 7 (clean, not a top dispatch).
__global__ __launch_bounds__(256) void k1a_pool(
    const float* __restrict__ feats, float* __restrict__ h_seq)
{
  const int bid = blockIdx.x;           // 16384 = 1024 t x 16 b-groups
  const int t = bid & (T_ - 1);
  const int b0 = (bid >> 10) << 3;      // 8 batch rows per block
  const int col = threadIdx.x;
  if (col < F_) {
    #pragma unroll
    for (int bb = 0; bb < 8; ++bb) {
      const float* p =
          feats + ((size_t)t * R_ + (size_t)(b0 + bb) * 4) * F_ + col;
      const float v =
          fmaxf(fmaxf(p[0], p[F_]), fmaxf(p[2 * F_], p[3 * F_]));
      h_seq[((size_t)(b0 + bb) * T_ + t) * F_ + col] = v;
    }
  }
}

// ---------------- K1b: GEMM  xg = h_seq @ W_ih^T + b_ih ----------------
// Round-4-proven structure (stage -> sync -> compute -> sync, LDS-direct, no
// register carry across compute, NO launch_bounds min-wave arg: round 7
// proved that arg mis-budgets VGPRs -> scratch spills -> 24x HBM traffic).
// Block = (b, 128 consecutive t): A slab is 124 KB contiguous in h_seq.
// 4 f-chunks of 64. As[128x64] (XOR-quad swizzle, validated conflict-free)
// + Ws[64x60] in LDS = 47 KB -> 3 blocks/CU.
__global__ __launch_bounds__(256) void k1b_gemm(
    const float* __restrict__ h_seq, const float* __restrict__ Wt,
    const float* __restrict__ b_ih, float* __restrict__ xg)
{
  __shared__ __align__(16) float As[128 * 64];   // 32 KB
  __shared__ __align__(16) float Ws[64 * 60];    // 15 KB
  const int bid = blockIdx.x;
  const int b = bid >> 3;
  const int t0 = (bid & 7) << 7;
  const int tid = threadIdx.x;
  const int rg = tid >> 4;                 // 0..15 -> rows rg*8..rg*8+7
  const int gcol = tid & 15;               // 0..15 -> gates gcol*4..+3
  const int gc4 = (gcol < 15) ? gcol * 4 : 56;   // clamp col 15 (dup of 14)

  const int srow0 = tid >> 6;              // 0..3 (stage rows srow0+4e)
  const int scol = tid & 63;               // stage col within chunk
  const float* hsb = h_seq + ((size_t)b * T_ + t0) * F_;

  float acc[8][4];
  #pragma unroll
  for (int i = 0; i < 8; ++i)
    #pragma unroll
    for (int j = 0; j < 4; ++j) acc[i][j] = 0.f;

#define STAGE(C, GUARD)                                                      \
  {                                                                          \
    const int FC = (C) * 64;                                                 \
    float at[32];                                                            \
    float wt[15];                                                            \
    _Pragma("unroll")                                                        \
    for (int e = 0; e < 32; ++e) {                                           \
      const int row = srow0 + 4 * e;                                         \
      at[e] = (!(GUARD) || (FC + scol < F_))                                 \
                  ? hsb[(size_t)row * F_ + FC + scol] : 0.f;                 \
    }                                                                        \
    _Pragma("unroll")                                                        \
    for (int k = 0; k < 15; ++k)                                             \
      wt[k] = Wt[(size_t)FC * G_ + tid + 256 * k];                           \
    _Pragma("unroll")                                                        \
    for (int e = 0; e < 32; ++e) {                                           \
      const int row = srow0 + 4 * e;                                         \
      As[(row << 6) + ((((scol >> 2) ^ (row >> 3)) & 15) << 2) +             \
         (scol & 3)] = at[e];                                                \
    }                                                                        \
    _Pragma("unroll")                                                        \
    for (int k = 0; k < 15; ++k) Ws[tid + 256 * k] = wt[k];                  \
  }

#define COMPUTE()                                                            \
  {                                                                          \
    _Pragma("unroll")                                                        \
    for (int fj = 0; fj < 16; ++fj) {                                        \
      const float* wp = &Ws[(fj * 4) * 60 + gc4];                            \
      const float4 w0 = *(const float4*)(wp);                                \
      const float4 w1 = *(const float4*)(wp + 60);                           \
      const float4 w2 = *(const float4*)(wp + 120);                          \
      const float4 w3 = *(const float4*)(wp + 180);                          \
      _Pragma("unroll")                                                      \
      for (int i = 0; i < 8; ++i) {                                          \
        const int row = (rg << 3) + i;                                       \
        const float4 a4 =                                                    \
            *(const float4*)&As[(row << 6) + (((fj ^ rg) & 15) << 2)];       \
        acc[i][0] = fmaf(a4.x, w0.x, fmaf(a4.y, w1.x, fmaf(a4.z, w2.x, fmaf(a4.w, w3.x, acc[i][0])))); \
        acc[i][1] = fmaf(a4.x, w0.y, fmaf(a4.y, w1.y, fmaf(a4.z, w2.y, fmaf(a4.w, w3.y, acc[i][1])))); \
        acc[i][2] = fmaf(a4.x, w0.z, fmaf(a4.y, w1.z, fmaf(a4.z, w2.z, fmaf(a4.w, w3.z, acc[i][2])))); \
        acc[i][3] = fmaf(a4.x, w0.w, fmaf(a4.y, w1.w, fmaf(a4.z, w2.w, fmaf(a4.w, w3.w, acc[i][3])))); \
      }                                                                      \
    }                                                                        \
  }

  STAGE(0, 0)
  __syncthreads();
  COMPUTE()
  __syncthreads();
  STAGE(1, 0)
  __syncthreads();
  COMPUTE()
  __syncthreads();
  STAGE(2, 0)
  __syncthreads();
  COMPUTE()
  __syncthreads();
  STAGE(3, 1)
  __syncthreads();
  COMPUTE()
#undef STAGE
#undef COMPUTE

  if (gcol < 15) {
    const float4 bi4 = *(const float4*)&b_ih[gc4];
    #pragma unroll
    for (int i = 0; i < 8; ++i) {
      const int row = (rg << 3) + i;
      float4 o;
      o.x = acc[i][0] + bi4.x;  o.y = acc[i][1] + bi4.y;
      o.z = acc[i][2] + bi4.z;  o.w = acc[i][3] + bi4.w;
      *(float4*)&xg[((size_t)b * T_ + t0 + row) * G_ + gc4] = o;
    }
  }
}

// ---------------- K2: recurrence only, zero cross-lane DS ops ----------------
// One wave per batch row. Lane j<20 owns the gate triple (r_j,z_j,n_j); the
// shared e vector lives in SGPR pairs via v_readlane; dots run as float2 math
// so the compiler can emit v_pk_fma_f32. e(t) goes into THIS block's own xg
// slab at packed offset (t-8)*20 (read >=8 steps earlier); t<8 -> ehead.
// NOTE: xg / e_store intentionally NOT __restrict__ (they alias).
__global__ __launch_bounds__(64) void k2_recur(
    const float* __restrict__ e0, const float* __restrict__ W_hh,
    const float* __restrict__ b_hh, const float* xg,
    float* e_store, float* __restrict__ ehead)
{
  const int b = blockIdx.x;
  const int lane = threadIdx.x;
  const bool own = lane < H_;
  const int j0 = own ? lane : 0;

  float2 wr2[10], wz2[10], wn2[10];
  #pragma unroll
  for (int k = 0; k < 10; ++k) {
    wr2[k] = *(const float2*)&W_hh[j0 * H_ + 2 * k];
    wz2[k] = *(const float2*)&W_hh[(j0 + 20) * H_ + 2 * k];
    wn2[k] = *(const float2*)&W_hh[(j0 + 40) * H_ + 2 * k];
  }
  const float bhr = b_hh[j0], bhz = b_hh[j0 + 20], bhn = b_hh[j0 + 40];

  float e_own = e0[b * H_ + j0];
  float2 es2[10];
  #pragma unroll
  for (int k = 0; k < 10; ++k) {
    es2[k].x = rdlane(e_own, 2 * k);
    es2[k].y = rdlane(e_own, 2 * k + 1);
  }

  const float* xgb = xg + (size_t)b * T_ * G_;
  float* xslab = e_store + (size_t)b * T_ * G_;   // packed e at (t-8)*20
  float* ehb = ehead + b * (P_ * H_);

  float xr[P_], xz[P_], xn[P_];
  #pragma unroll
  for (int j = 0; j < P_; ++j) {
    xr[j] = xgb[(size_t)j * G_ + j0];
    xz[j] = xgb[(size_t)j * G_ + j0 + 20];
    xn[j] = xgb[(size_t)j * G_ + j0 + 40];
  }

#define STEP(j, RELOAD)                                                    \
  {                                                                        \
    const int t = t0 + (j);                                                \
    const float xrv = xr[j], xzv = xz[j], xnv = xn[j];                     \
    if (RELOAD) {                                                          \
      const float* xp = xgb + (size_t)(t + P_) * G_;                       \
      xr[j] = xp[j0]; xz[j] = xp[j0 + 20]; xn[j] = xp[j0 + 40];            \
    }                                                                      \
    float2 r2 = make_float2(bhr, 0.f);                                     \
    float2 z2 = make_float2(bhz, 0.f);                                     \
    float2 n2 = make_float2(bhn, 0.f);                                     \
    _Pragma("unroll")                                                      \
    for (int k = 0; k < 10; ++k) {                                         \
      r2 = wr2[k] * es2[k] + r2;                                           \
      z2 = wz2[k] * es2[k] + z2;                                           \
      n2 = wn2[k] * es2[k] + n2;                                           \
    }                                                                      \
    const float hr = r2.x + r2.y, hz = z2.x + z2.y, hn = n2.x + n2.y;      \
    const float rg = 1.f / (1.f + __expf(-(xrv + hr)));                    \
    const float zg = 1.f / (1.f + __expf(-(xzv + hz)));                    \
    const float aa = xnv + rg * hn;                                        \
    const float ng = 1.f - 2.f / (__expf(2.f * aa) + 1.f);                 \
    const float enew = (1.f - zg) * ng + zg * e_own;                       \
    if (own) {                                                             \
      float* dst = (t >= P_) ? (xslab + (size_t)(t - P_) * H_ + lane)      \
                             : (ehb + t * H_ + lane);                      \
      *dst = enew;                                                         \
    }                                                                      \
    e_own = enew;                                                          \
    _Pragma("unroll")                                                      \
    for (int k = 0; k < 10; ++k) {                                         \
      es2[k].x = rdlane(enew, 2 * k);                                      \
      es2[k].y = rdlane(enew, 2 * k + 1);                                  \
    }                                                                      \
  }

  for (int t0 = 0; t0 < T_ - P_; t0 += P_) {
    STEP(0, true) STEP(1, true) STEP(2, true) STEP(3, true)
    STEP(4, true) STEP(5, true) STEP(6, true) STEP(7, true)
  }
  {
    const int t0 = T_ - P_;
    STEP(0, false) STEP(1, false) STEP(2, false) STEP(3, false)
    STEP(4, false) STEP(5, false) STEP(6, false) STEP(7, false)
  }
#undef STEP
}

// ---------------- K4: decoder + squared-error ----------------
#define K4_ROWS 128
__global__ __launch_bounds__(256) void k4_decode(
    const float* __restrict__ W_dec, const float* __restrict__ b_dec,
    const float* __restrict__ h_seq, const float* __restrict__ e_store,
    const float* __restrict__ ehead, float* __restrict__ partials)
{
  __shared__ float elds[K4_ROWS * H_];   // 10 KB
  __shared__ float red[4];
  const int tid = threadIdx.x;
  const int f = tid;
  const bool act = f < F_;
  const int lane = tid & 63, wave = tid >> 6;
  const size_t r0 = (size_t)blockIdx.x * K4_ROWS;
  const int b = (int)(r0 >> 10);
  const int t0 = (int)(r0 & (T_ - 1));
  const float* xslab = e_store + (size_t)b * T_ * G_;
  const float* ehb = ehead + b * (P_ * H_);

  for (int i = tid; i < K4_ROWS * H_; i += 256) {
    const int trow = i / H_;
    const int c = i - trow * H_;
    const int t = t0 + trow;
    elds[i] = (t >= P_) ? xslab[(size_t)(t - P_) * H_ + c] : ehb[t * H_ + c];
  }

  float wd[H_];
  float bd = 0.f;
  if (act) {
    #pragma unroll
    for (int k = 0; k < H_; ++k) wd[k] = W_dec[f * H_ + k];
    bd = b_dec[f];
  }
  __syncthreads();

  float acc = 0.f;
  #pragma unroll 2
  for (int i = 0; i < K4_ROWS; ++i) {
    const float2* ep = (const float2*)&elds[i * H_];
    float d = bd;
    #pragma unroll
    for (int k = 0; k < 10; ++k) {
      const float2 e2 = ep[k];
      d = fmaf(wd[2 * k], e2.x, fmaf(wd[2 * k + 1], e2.y, d));
    }
    const float fo = fmaxf(d, 0.f);
    if (act) {
      const float h = h_seq[(r0 + i) * F_ + f];
      const float df = fo - h;
      acc = fmaf(df, df, acc);
    }
  }

  #pragma unroll
  for (int m = 32; m >= 1; m >>= 1) acc += __shfl_xor(acc, m);
  if (lane == 0) red[wave] = acc;
  __syncthreads();
  if (tid == 0) partials[blockIdx.x] = red[0] + red[1] + red[2] + red[3];
}

// ---------------- K3: final deterministic reduction over 1024 partials ----------------
__global__ __launch_bounds__(64) void k3_reduce(
    const float* __restrict__ partials, float* __restrict__ out)
{
  const int lane = threadIdx.x;
  float a = 0.f;
  #pragma unroll
  for (int i = 0; i < 16; ++i) a += partials[i * 64 + lane];
  #pragma unroll
  for (int m = 32; m >= 1; m >>= 1) a += __shfl_xor(a, m);
  if (lane == 0) out[0] = a * (float)(1.0 / ((double)T_ * B_ * F_));
}

extern "C" void kernel_launch(void* const* d_in, const int* in_sizes, int n_in,
                              void* d_out, int out_size, void* d_ws, size_t ws_size,
                              hipStream_t stream) {
  const float* feats = (const float*)d_in[0];
  const float* e0    = (const float*)d_in[1];
  const float* W_ih  = (const float*)d_in[2];
  const float* W_hh  = (const float*)d_in[3];
  const float* b_ih  = (const float*)d_in[4];
  const float* b_hh  = (const float*)d_in[5];
  const float* W_dec = (const float*)d_in[6];
  const float* b_dec = (const float*)d_in[7];
  float* out = (float*)d_out;

  float* ws = (float*)d_ws;
  float* h_seq    = ws;                                    // B*T*F floats (b-major)
  float* xgates   = ws + (size_t)T_ * B_ * F_;             // B*T*G floats (b-major)
  float* partials = xgates + (size_t)T_ * B_ * G_;         // 1024 floats
  float* ehead    = partials + 1024;                       // B*8*H floats (e for t<8)
  float* Wt       = ehead + B_ * P_ * H_;                  // FP_*G_ floats

  hipLaunchKernelGGL(k0_wt, dim3(60), dim3(256), 0, stream, W_ih, Wt);
  hipLaunchKernelGGL(k1a_pool, dim3(T_ * (B_ / 8)), dim3(256), 0, stream,
                     feats, h_seq);
  hipLaunchKernelGGL(k1b_gemm, dim3(B_ * 8), dim3(256), 0, stream,
                     h_seq, Wt, b_ih, xgates);
  hipLaunchKernelGGL(k2_recur, dim3(B_), dim3(64), 0, stream,
                     e0, W_hh, b_hh, xgates, xgates, ehead);
  hipLaunchKernelGGL(k4_decode, dim3((T_ * B_) / K4_ROWS), dim3(256), 0, stream,
                     W_dec, b_dec, h_seq, xgates, ehead, partials);
  hipLaunchKernelGGL(k3_reduce, dim3(1), dim3(64), 0, stream,
                     partials, out);
}

// Round 9
// 548.817 us; speedup vs baseline: 4.0706x; 2.8971x over previous
//
#include <hip/hip_runtime.h>
#include <cstddef>

#define T_ 1024
#define B_ 128
#define F_ 243
#define H_ 20
#define G_ 60   // 3*H
#define R_ 512  // B*POOL
#define P_ 8    // xg prefetch depth in k2 (also the e-store shift)
#define FP_ 256 // padded F for Wt (f-major transposed W_ih)
#define HS_ 244 // h_seq row stride: 244 floats = 976 B = 61*16 -> 16-B aligned rows

__device__ __forceinline__ float rdlane(float v, int l) {
  return __int_as_float(__builtin_amdgcn_readlane(__float_as_int(v), l));
}

// ---------------- K0: transpose W_ih -> Wt[256][60] (f-major, zero-padded) ----------------
// Rows f>=243 are ZERO: k1b relies on this to null out h_seq's pad columns.
__global__ __launch_bounds__(256) void k0_wt(
    const float* __restrict__ W_ih, float* __restrict__ Wt)
{
  const int i = blockIdx.x * 256 + threadIdx.x;   // 60 blocks -> 15360 = FP_*G_
  if (i < FP_ * G_) {
    const int f = i / G_, g = i - f * G_;
    Wt[(size_t)f * G_ + g] = (f < F_) ? W_ih[(size_t)g * F_ + f] : 0.f;
  }
}

// ---------------- K1a: pure streaming max-pool(4): feats -> h_seq (b-major, stride 244) ---
// Fully contiguous 972-B reads/writes, no LDS, no barriers. Validated round 7/8.
__global__ __launch_bounds__(256) void k1a_pool(
    const float* __restrict__ feats, float* __restrict__ h_seq)
{
  const int bid = blockIdx.x;           // 16384 = 1024 t x 16 b-groups
  const int t = bid & (T_ - 1);
  const int b0 = (bid >> 10) << 3;      // 8 batch rows per block
  const int col = threadIdx.x;
  if (col < F_) {
    #pragma unroll
    for (int bb = 0; bb < 8; ++bb) {
      const float* p =
          feats + ((size_t)t * R_ + (size_t)(b0 + bb) * 4) * F_ + col;
      const float v =
          fmaxf(fmaxf(p[0], p[F_]), fmaxf(p[2 * F_], p[3 * F_]));
      h_seq[((size_t)(b0 + bb) * T_ + t) * HS_ + col] = v;
    }
  }
}

// ---------------- K1b: GEMM  xg = h_seq @ W_ih^T + b_ih  (NO A-tile) ----------------
// Rounds 7-8 lesson: any register-array staging of A gets its unrolled load
// chain hoisted by the scheduler -> VGPR cap -> scratch spill -> GBs of HBM.
// Here A is read DIRECTLY from global: the 16 lanes of a rg-group load the
// SAME float4 (coalescer collapses to one request; per-wave line set ~4 KB ->
// L1-resident), so DRAM sees only the unique 128 MB. Every load is consumed
// immediately by 16 FMAs -> nothing to hoist. Only Ws (15 KB/chunk) in LDS.
// h_seq stride 244 makes all float4 A-loads 16-B aligned; pad cols hit the
// zero rows of Wt (k0) so chunk 3's overrun contributes exactly 0.
__global__ __launch_bounds__(256) void k1b_gemm(
    const float* __restrict__ h_seq, const float* __restrict__ Wt,
    const float* __restrict__ b_ih, float* __restrict__ xg)
{
  __shared__ __align__(16) float Ws[64 * 60];    // 15 KB, f-major chunk
  const int bid = blockIdx.x;
  const int b = bid >> 3;
  const int t0 = (bid & 7) << 7;           // 8 t-chunks of 128 rows
  const int tid = threadIdx.x;
  const int rg = tid >> 4;                 // 0..15 -> rows rg*8..rg*8+7
  const int gcol = tid & 15;               // 0..15 -> gates gcol*4..+3
  const int gc4 = (gcol < 15) ? gcol * 4 : 56;   // clamp col 15 (dup of 14)
  const float* hsb = h_seq + ((size_t)b * T_ + t0) * HS_;

  float acc[8][4];
  #pragma unroll
  for (int i = 0; i < 8; ++i)
    #pragma unroll
    for (int j = 0; j < 4; ++j) acc[i][j] = 0.f;

  for (int c = 0; c < 4; ++c) {            // f-chunks of 64
    const int FC = c * 64;
    __syncthreads();                       // Ws readers of chunk c-1 done
    for (int j = tid; j < 64 * 60; j += 256)
      Ws[j] = Wt[(size_t)FC * G_ + j];
    __syncthreads();
    #pragma unroll
    for (int fj = 0; fj < 16; ++fj) {
      const float* wp = &Ws[(fj * 4) * 60 + gc4];
      const float4 w0 = *(const float4*)(wp);
      const float4 w1 = *(const float4*)(wp + 60);
      const float4 w2 = *(const float4*)(wp + 120);
      const float4 w3 = *(const float4*)(wp + 180);
      #pragma unroll
      for (int i = 0; i < 8; ++i) {
        const int row = (rg << 3) + i;
        const float4 a4 =
            *(const float4*)&hsb[(size_t)row * HS_ + FC + fj * 4];
        acc[i][0] = fmaf(a4.x, w0.x, fmaf(a4.y, w1.x, fmaf(a4.z, w2.x, fmaf(a4.w, w3.x, acc[i][0]))));
        acc[i][1] = fmaf(a4.x, w0.y, fmaf(a4.y, w1.y, fmaf(a4.z, w2.y, fmaf(a4.w, w3.y, acc[i][1]))));
        acc[i][2] = fmaf(a4.x, w0.z, fmaf(a4.y, w1.z, fmaf(a4.z, w2.z, fmaf(a4.w, w3.z, acc[i][2]))));
        acc[i][3] = fmaf(a4.x, w0.w, fmaf(a4.y, w1.w, fmaf(a4.z, w2.w, fmaf(a4.w, w3.w, acc[i][3]))));
      }
    }
  }

  if (gcol < 15) {
    const float4 bi4 = *(const float4*)&b_ih[gc4];
    #pragma unroll
    for (int i = 0; i < 8; ++i) {
      const int row = (rg << 3) + i;
      float4 o;
      o.x = acc[i][0] + bi4.x;  o.y = acc[i][1] + bi4.y;
      o.z = acc[i][2] + bi4.z;  o.w = acc[i][3] + bi4.w;
      *(float4*)&xg[((size_t)b * T_ + t0 + row) * G_ + gc4] = o;
    }
  }
}

// ---------------- K2: recurrence only, zero cross-lane DS ops ----------------
// One wave per batch row. Lane j<20 owns the gate triple (r_j,z_j,n_j); the
// shared e vector lives in SGPR pairs via v_readlane; dots run as float2 math
// so the compiler can emit v_pk_fma_f32. e(t) goes into THIS block's own xg
// slab at packed offset (t-8)*20 (read >=8 steps earlier); t<8 -> ehead.
// NOTE: xg / e_store intentionally NOT __restrict__ (they alias).
__global__ __launch_bounds__(64) void k2_recur(
    const float* __restrict__ e0, const float* __restrict__ W_hh,
    const float* __restrict__ b_hh, const float* xg,
    float* e_store, float* __restrict__ ehead)
{
  const int b = blockIdx.x;
  const int lane = threadIdx.x;
  const bool own = lane < H_;
  const int j0 = own ? lane : 0;

  float2 wr2[10], wz2[10], wn2[10];
  #pragma unroll
  for (int k = 0; k < 10; ++k) {
    wr2[k] = *(const float2*)&W_hh[j0 * H_ + 2 * k];
    wz2[k] = *(const float2*)&W_hh[(j0 + 20) * H_ + 2 * k];
    wn2[k] = *(const float2*)&W_hh[(j0 + 40) * H_ + 2 * k];
  }
  const float bhr = b_hh[j0], bhz = b_hh[j0 + 20], bhn = b_hh[j0 + 40];

  float e_own = e0[b * H_ + j0];
  float2 es2[10];
  #pragma unroll
  for (int k = 0; k < 10; ++k) {
    es2[k].x = rdlane(e_own, 2 * k);
    es2[k].y = rdlane(e_own, 2 * k + 1);
  }

  const float* xgb = xg + (size_t)b * T_ * G_;
  float* xslab = e_store + (size_t)b * T_ * G_;   // packed e at (t-8)*20
  float* ehb = ehead + b * (P_ * H_);

  float xr[P_], xz[P_], xn[P_];
  #pragma unroll
  for (int j = 0; j < P_; ++j) {
    xr[j] = xgb[(size_t)j * G_ + j0];
    xz[j] = xgb[(size_t)j * G_ + j0 + 20];
    xn[j] = xgb[(size_t)j * G_ + j0 + 40];
  }

#define STEP(j, RELOAD)                                                    \
  {                                                                        \
    const int t = t0 + (j);                                                \
    const float xrv = xr[j], xzv = xz[j], xnv = xn[j];                     \
    if (RELOAD) {                                                          \
      const float* xp = xgb + (size_t)(t + P_) * G_;                       \
      xr[j] = xp[j0]; xz[j] = xp[j0 + 20]; xn[j] = xp[j0 + 40];            \
    }                                                                      \
    float2 r2 = make_float2(bhr, 0.f);                                     \
    float2 z2 = make_float2(bhz, 0.f);                                     \
    float2 n2 = make_float2(bhn, 0.f);                                     \
    _Pragma("unroll")                                                      \
    for (int k = 0; k < 10; ++k) {                                         \
      r2 = wr2[k] * es2[k] + r2;                                           \
      z2 = wz2[k] * es2[k] + z2;                                           \
      n2 = wn2[k] * es2[k] + n2;                                           \
    }                                                                      \
    const float hr = r2.x + r2.y, hz = z2.x + z2.y, hn = n2.x + n2.y;      \
    const float rg = 1.f / (1.f + __expf(-(xrv + hr)));                    \
    const float zg = 1.f / (1.f + __expf(-(xzv + hz)));                    \
    const float aa = xnv + rg * hn;                                        \
    const float ng = 1.f - 2.f / (__expf(2.f * aa) + 1.f);                 \
    const float enew = (1.f - zg) * ng + zg * e_own;                       \
    if (own) {                                                             \
      float* dst = (t >= P_) ? (xslab + (size_t)(t - P_) * H_ + lane)      \
                             : (ehb + t * H_ + lane);                      \
      *dst = enew;                                                         \
    }                                                                      \
    e_own = enew;                                                          \
    _Pragma("unroll")                                                      \
    for (int k = 0; k < 10; ++k) {                                         \
      es2[k].x = rdlane(enew, 2 * k);                                      \
      es2[k].y = rdlane(enew, 2 * k + 1);                                  \
    }                                                                      \
  }

  for (int t0 = 0; t0 < T_ - P_; t0 += P_) {
    STEP(0, true) STEP(1, true) STEP(2, true) STEP(3, true)
    STEP(4, true) STEP(5, true) STEP(6, true) STEP(7, true)
  }
  {
    const int t0 = T_ - P_;
    STEP(0, false) STEP(1, false) STEP(2, false) STEP(3, false)
    STEP(4, false) STEP(5, false) STEP(6, false) STEP(7, false)
  }
#undef STEP
}

// ---------------- K4: decoder + squared-error ----------------
#define K4_ROWS 128
__global__ __launch_bounds__(256) void k4_decode(
    const float* __restrict__ W_dec, const float* __restrict__ b_dec,
    const float* __restrict__ h_seq, const float* __restrict__ e_store,
    const float* __restrict__ ehead, float* __restrict__ partials)
{
  __shared__ float elds[K4_ROWS * H_];   // 10 KB
  __shared__ float red[4];
  const int tid = threadIdx.x;
  const int f = tid;
  const bool act = f < F_;
  const int lane = tid & 63, wave = tid >> 6;
  const size_t r0 = (size_t)blockIdx.x * K4_ROWS;
  const int b = (int)(r0 >> 10);
  const int t0 = (int)(r0 & (T_ - 1));
  const float* xslab = e_store + (size_t)b * T_ * G_;
  const float* ehb = ehead + b * (P_ * H_);

  for (int i = tid; i < K4_ROWS * H_; i += 256) {
    const int trow = i / H_;
    const int c = i - trow * H_;
    const int t = t0 + trow;
    elds[i] = (t >= P_) ? xslab[(size_t)(t - P_) * H_ + c] : ehb[t * H_ + c];
  }

  float wd[H_];
  float bd = 0.f;
  if (act) {
    #pragma unroll
    for (int k = 0; k < H_; ++k) wd[k] = W_dec[f * H_ + k];
    bd = b_dec[f];
  }
  __syncthreads();

  float acc = 0.f;
  #pragma unroll 2
  for (int i = 0; i < K4_ROWS; ++i) {
    const float2* ep = (const float2*)&elds[i * H_];
    float d = bd;
    #pragma unroll
    for (int k = 0; k < 10; ++k) {
      const float2 e2 = ep[k];
      d = fmaf(wd[2 * k], e2.x, fmaf(wd[2 * k + 1], e2.y, d));
    }
    const float fo = fmaxf(d, 0.f);
    if (act) {
      const float h = h_seq[(r0 + i) * HS_ + f];
      const float df = fo - h;
      acc = fmaf(df, df, acc);
    }
  }

  #pragma unroll
  for (int m = 32; m >= 1; m >>= 1) acc += __shfl_xor(acc, m);
  if (lane == 0) red[wave] = acc;
  __syncthreads();
  if (tid == 0) partials[blockIdx.x] = red[0] + red[1] + red[2] + red[3];
}

// ---------------- K3: final deterministic reduction over 1024 partials ----------------
__global__ __launch_bounds__(64) void k3_reduce(
    const float* __restrict__ partials, float* __restrict__ out)
{
  const int lane = threadIdx.x;
  float a = 0.f;
  #pragma unroll
  for (int i = 0; i < 16; ++i) a += partials[i * 64 + lane];
  #pragma unroll
  for (int m = 32; m >= 1; m >>= 1) a += __shfl_xor(a, m);
  if (lane == 0) out[0] = a * (float)(1.0 / ((double)T_ * B_ * F_));
}

extern "C" void kernel_launch(void* const* d_in, const int* in_sizes, int n_in,
                              void* d_out, int out_size, void* d_ws, size_t ws_size,
                              hipStream_t stream) {
  const float* feats = (const float*)d_in[0];
  const float* e0    = (const float*)d_in[1];
  const float* W_ih  = (const float*)d_in[2];
  const float* W_hh  = (const float*)d_in[3];
  const float* b_ih  = (const float*)d_in[4];
  const float* b_hh  = (const float*)d_in[5];
  const float* W_dec = (const float*)d_in[6];
  const float* b_dec = (const float*)d_in[7];
  float* out = (float*)d_out;

  float* ws = (float*)d_ws;
  float* h_seq    = ws;                                    // B*T*HS_ floats (b-major, padded)
  float* xgates   = ws + (size_t)B_ * T_ * HS_;            // B*T*G floats (b-major)
  float* partials = xgates + (size_t)T_ * B_ * G_;         // 1024 floats
  float* ehead    = partials + 1024;                       // B*8*H floats (e for t<8)
  float* Wt       = ehead + B_ * P_ * H_;                  // FP_*G_ floats

  hipLaunchKernelGGL(k0_wt, dim3(60), dim3(256), 0, stream, W_ih, Wt);
  hipLaunchKernelGGL(k1a_pool, dim3(T_ * (B_ / 8)), dim3(256), 0, stream,
                     feats, h_seq);
  hipLaunchKernelGGL(k1b_gemm, dim3(B_ * 8), dim3(256), 0, stream,
                     h_seq, Wt, b_ih, xgates);
  hipLaunchKernelGGL(k2_recur, dim3(B_), dim3(64), 0, stream,
                     e0, W_hh, b_hh, xgates, xgates, ehead);
  hipLaunchKernelGGL(k4_decode, dim3((T_ * B_) / K4_ROWS), dim3(256), 0, stream,
                     W_dec, b_dec, h_seq, xgates, ehead, partials);
  hipLaunchKernelGGL(k3_reduce, dim3(1), dim3(64), 0, stream,
                     partials, out);
}

// Round 10
// 495.038 us; speedup vs baseline: 4.5128x; 1.1086x over previous
//
#include <hip/hip_runtime.h>
#include <cstddef>

#define T_ 1024
#define B_ 128
#define F_ 243
#define H_ 20
#define G_ 60   // 3*H
#define R_ 512  // B*POOL
#define P_ 8    // xg prefetch depth in k2 (also the e-store shift)
#define FP_ 256 // padded F for Wt (f-major transposed W_ih)
#define HS_ 244 // h_seq row stride: 244 floats = 976 B = 61*16 -> 16-B aligned rows

__device__ __forceinline__ float rdlane(float v, int l) {
  return __int_as_float(__builtin_amdgcn_readlane(__float_as_int(v), l));
}
#define RCP(x) __builtin_amdgcn_rcpf(x)

// ---------------- K1a: streaming max-pool(4): feats -> h_seq (b-major, stride 244) -------
// Fully contiguous 972-B reads/writes, no LDS, no barriers (validated r7-r9).
// Blocks 0..59 additionally build Wt[256][60] (f-major transpose of W_ih,
// rows f>=243 zero -- k1b relies on the zero rows to null h_seq's pad cols);
// k1b launches after k1a so Wt is complete when consumed.
__global__ __launch_bounds__(256) void k1a_pool(
    const float* __restrict__ feats, float* __restrict__ h_seq,
    const float* __restrict__ W_ih, float* __restrict__ Wt)
{
  const int bid = blockIdx.x;           // 16384 = 1024 t x 16 b-groups
  if (bid < 60) {                       // folded k0: 60*256 >= FP_*G_
    const int i = bid * 256 + threadIdx.x;
    if (i < FP_ * G_) {
      const int f = i / G_, g = i - f * G_;
      Wt[(size_t)f * G_ + g] = (f < F_) ? W_ih[(size_t)g * F_ + f] : 0.f;
    }
  }
  const int t = bid & (T_ - 1);
  const int b0 = (bid >> 10) << 3;      // 8 batch rows per block
  const int col = threadIdx.x;
  if (col < F_) {
    #pragma unroll
    for (int bb = 0; bb < 8; ++bb) {
      const float* p =
          feats + ((size_t)t * R_ + (size_t)(b0 + bb) * 4) * F_ + col;
      const float v =
          fmaxf(fmaxf(p[0], p[F_]), fmaxf(p[2 * F_], p[3 * F_]));
      h_seq[((size_t)(b0 + bb) * T_ + t) * HS_ + col] = v;
    }
  }
}

// ---------------- K1b: GEMM  xg = h_seq @ W_ih^T + b_ih  (NO A-tile; validated r9) -------
// A read directly from global: the 16 lanes of a rg-group load the SAME
// float4 (coalescer collapses; per-wave line set L1-resident), consumed
// immediately by 16 FMAs -> nothing for the scheduler to hoist, no spills.
// Only Ws (15 KB/chunk) in LDS. h_seq stride 244 keeps loads 16-B aligned.
__global__ __launch_bounds__(256) void k1b_gemm(
    const float* __restrict__ h_seq, const float* __restrict__ Wt,
    const float* __restrict__ b_ih, float* __restrict__ xg)
{
  __shared__ __align__(16) float Ws[64 * 60];    // 15 KB, f-major chunk
  const int bid = blockIdx.x;
  const int b = bid >> 3;
  const int t0 = (bid & 7) << 7;           // 8 t-chunks of 128 rows
  const int tid = threadIdx.x;
  const int rg = tid >> 4;                 // 0..15 -> rows rg*8..rg*8+7
  const int gcol = tid & 15;               // 0..15 -> gates gcol*4..+3
  const int gc4 = (gcol < 15) ? gcol * 4 : 56;   // clamp col 15 (dup of 14)
  const float* hsb = h_seq + ((size_t)b * T_ + t0) * HS_;

  float acc[8][4];
  #pragma unroll
  for (int i = 0; i < 8; ++i)
    #pragma unroll
    for (int j = 0; j < 4; ++j) acc[i][j] = 0.f;

  for (int c = 0; c < 4; ++c) {            // f-chunks of 64
    const int FC = c * 64;
    __syncthreads();                       // Ws readers of chunk c-1 done
    for (int j = tid; j < 64 * 60; j += 256)
      Ws[j] = Wt[(size_t)FC * G_ + j];
    __syncthreads();
    #pragma unroll
    for (int fj = 0; fj < 16; ++fj) {
      const float* wp = &Ws[(fj * 4) * 60 + gc4];
      const float4 w0 = *(const float4*)(wp);
      const float4 w1 = *(const float4*)(wp + 60);
      const float4 w2 = *(const float4*)(wp + 120);
      const float4 w3 = *(const float4*)(wp + 180);
      #pragma unroll
      for (int i = 0; i < 8; ++i) {
        const int row = (rg << 3) + i;
        const float4 a4 =
            *(const float4*)&hsb[(size_t)row * HS_ + FC + fj * 4];
        acc[i][0] = fmaf(a4.x, w0.x, fmaf(a4.y, w1.x, fmaf(a4.z, w2.x, fmaf(a4.w, w3.x, acc[i][0]))));
        acc[i][1] = fmaf(a4.x, w0.y, fmaf(a4.y, w1.y, fmaf(a4.z, w2.y, fmaf(a4.w, w3.y, acc[i][1]))));
        acc[i][2] = fmaf(a4.x, w0.z, fmaf(a4.y, w1.z, fmaf(a4.z, w2.z, fmaf(a4.w, w3.z, acc[i][2]))));
        acc[i][3] = fmaf(a4.x, w0.w, fmaf(a4.y, w1.w, fmaf(a4.z, w2.w, fmaf(a4.w, w3.w, acc[i][3]))));
      }
    }
  }

  if (gcol < 15) {
    const float4 bi4 = *(const float4*)&b_ih[gc4];
    #pragma unroll
    for (int i = 0; i < 8; ++i) {
      const int row = (rg << 3) + i;
      float4 o;
      o.x = acc[i][0] + bi4.x;  o.y = acc[i][1] + bi4.y;
      o.z = acc[i][2] + bi4.z;  o.w = acc[i][3] + bi4.w;
      *(float4*)&xg[((size_t)b * T_ + t0 + row) * G_ + gc4] = o;
    }
  }
}

// ---------------- K2: recurrence only, zero cross-lane DS ops ----------------
// One wave per batch row; lane j<20 owns the gate triple (r_j,z_j,n_j); the
// shared e vector lives in SGPR pairs via v_readlane. This round: all three
// reciprocals via v_rcp_f32 (the 1.f/x form compiled to full IEEE div
// sequences -- 3 x ~25cy on the serial chain) and each dot split into 2
// accumulators (chain 10 -> 5 deep). e(t) goes into THIS block's own xg slab
// at packed offset (t-8)*20 (read >=8 steps earlier); t<8 -> ehead.
// NOTE: xg / e_store intentionally NOT __restrict__ (they alias).
__global__ __launch_bounds__(64) void k2_recur(
    const float* __restrict__ e0, const float* __restrict__ W_hh,
    const float* __restrict__ b_hh, const float* xg,
    float* e_store, float* __restrict__ ehead)
{
  const int b = blockIdx.x;
  const int lane = threadIdx.x;
  const bool own = lane < H_;
  const int j0 = own ? lane : 0;

  float2 wr2[10], wz2[10], wn2[10];
  #pragma unroll
  for (int k = 0; k < 10; ++k) {
    wr2[k] = *(const float2*)&W_hh[j0 * H_ + 2 * k];
    wz2[k] = *(const float2*)&W_hh[(j0 + 20) * H_ + 2 * k];
    wn2[k] = *(const float2*)&W_hh[(j0 + 40) * H_ + 2 * k];
  }
  const float bhr = b_hh[j0], bhz = b_hh[j0 + 20], bhn = b_hh[j0 + 40];

  float e_own = e0[b * H_ + j0];
  float2 es2[10];
  #pragma unroll
  for (int k = 0; k < 10; ++k) {
    es2[k].x = rdlane(e_own, 2 * k);
    es2[k].y = rdlane(e_own, 2 * k + 1);
  }

  const float* xgb = xg + (size_t)b * T_ * G_;
  float* xslab = e_store + (size_t)b * T_ * G_;   // packed e at (t-8)*20
  float* ehb = ehead + b * (P_ * H_);

  float xr[P_], xz[P_], xn[P_];
  #pragma unroll
  for (int j = 0; j < P_; ++j) {
    xr[j] = xgb[(size_t)j * G_ + j0];
    xz[j] = xgb[(size_t)j * G_ + j0 + 20];
    xn[j] = xgb[(size_t)j * G_ + j0 + 40];
  }

#define STEP(j, RELOAD)                                                    \
  {                                                                        \
    const int t = t0 + (j);                                                \
    const float xrv = xr[j], xzv = xz[j], xnv = xn[j];                     \
    if (RELOAD) {                                                          \
      const float* xp = xgb + (size_t)(t + P_) * G_;                       \
      xr[j] = xp[j0]; xz[j] = xp[j0 + 20]; xn[j] = xp[j0 + 40];            \
    }                                                                      \
    float2 rA = make_float2(bhr, 0.f), rB = make_float2(0.f, 0.f);         \
    float2 zA = make_float2(bhz, 0.f), zB = make_float2(0.f, 0.f);         \
    float2 nA = make_float2(bhn, 0.f), nB = make_float2(0.f, 0.f);         \
    _Pragma("unroll")                                                      \
    for (int k = 0; k < 5; ++k) {                                          \
      rA = wr2[k] * es2[k] + rA;   rB = wr2[k + 5] * es2[k + 5] + rB;      \
      zA = wz2[k] * es2[k] + zA;   zB = wz2[k + 5] * es2[k + 5] + zB;      \
      nA = wn2[k] * es2[k] + nA;   nB = wn2[k + 5] * es2[k + 5] + nB;      \
    }                                                                      \
    const float hr = (rA.x + rB.x) + (rA.y + rB.y);                        \
    const float hz = (zA.x + zB.x) + (zA.y + zB.y);                        \
    const float hn = (nA.x + nB.x) + (nA.y + nB.y);                        \
    const float rg = RCP(1.f + __expf(-(xrv + hr)));                       \
    const float zg = RCP(1.f + __expf(-(xzv + hz)));                       \
    const float aa = xnv + rg * hn;                                        \
    const float ng = 1.f - 2.f * RCP(__expf(2.f * aa) + 1.f);              \
    const float enew = (1.f - zg) * ng + zg * e_own;                       \
    if (own) {                                                             \
      float* dst = (t >= P_) ? (xslab + (size_t)(t - P_) * H_ + lane)      \
                             : (ehb + t * H_ + lane);                      \
      *dst = enew;                                                         \
    }                                                                      \
    e_own = enew;                                                          \
    _Pragma("unroll")                                                      \
    for (int k = 0; k < 10; ++k) {                                         \
      es2[k].x = rdlane(enew, 2 * k);                                      \
      es2[k].y = rdlane(enew, 2 * k + 1);                                  \
    }                                                                      \
  }

  for (int t0 = 0; t0 < T_ - P_; t0 += P_) {
    STEP(0, true) STEP(1, true) STEP(2, true) STEP(3, true)
    STEP(4, true) STEP(5, true) STEP(6, true) STEP(7, true)
  }
  {
    const int t0 = T_ - P_;
    STEP(0, false) STEP(1, false) STEP(2, false) STEP(3, false)
    STEP(4, false) STEP(5, false) STEP(6, false) STEP(7, false)
  }
#undef STEP
}

// ---------------- K4: decoder + squared-error (validated r9) ----------------
#define K4_ROWS 128
__global__ __launch_bounds__(256) void k4_decode(
    const float* __restrict__ W_dec, const float* __restrict__ b_dec,
    const float* __restrict__ h_seq, const float* __restrict__ e_store,
    const float* __restrict__ ehead, float* __restrict__ partials)
{
  __shared__ float elds[K4_ROWS * H_];   // 10 KB
  __shared__ float red[4];
  const int tid = threadIdx.x;
  const int f = tid;
  const bool act = f < F_;
  const int lane = tid & 63, wave = tid >> 6;
  const size_t r0 = (size_t)blockIdx.x * K4_ROWS;
  const int b = (int)(r0 >> 10);
  const int t0 = (int)(r0 & (T_ - 1));
  const float* xslab = e_store + (size_t)b * T_ * G_;
  const float* ehb = ehead + b * (P_ * H_);

  for (int i = tid; i < K4_ROWS * H_; i += 256) {
    const int trow = i / H_;
    const int c = i - trow * H_;
    const int t = t0 + trow;
    elds[i] = (t >= P_) ? xslab[(size_t)(t - P_) * H_ + c] : ehb[t * H_ + c];
  }

  float wd[H_];
  float bd = 0.f;
  if (act) {
    #pragma unroll
    for (int k = 0; k < H_; ++k) wd[k] = W_dec[f * H_ + k];
    bd = b_dec[f];
  }
  __syncthreads();

  float acc = 0.f;
  #pragma unroll 2
  for (int i = 0; i < K4_ROWS; ++i) {
    const float2* ep = (const float2*)&elds[i * H_];
    float d = bd;
    #pragma unroll
    for (int k = 0; k < 10; ++k) {
      const float2 e2 = ep[k];
      d = fmaf(wd[2 * k], e2.x, fmaf(wd[2 * k + 1], e2.y, d));
    }
    const float fo = fmaxf(d, 0.f);
    if (act) {
      const float h = h_seq[(r0 + i) * HS_ + f];
      const float df = fo - h;
      acc = fmaf(df, df, acc);
    }
  }

  #pragma unroll
  for (int m = 32; m >= 1; m >>= 1) acc += __shfl_xor(acc, m);
  if (lane == 0) red[wave] = acc;
  __syncthreads();
  if (tid == 0) partials[blockIdx.x] = red[0] + red[1] + red[2] + red[3];
}

// ---------------- K3: final deterministic reduction over 1024 partials ----------------
__global__ __launch_bounds__(64) void k3_reduce(
    const float* __restrict__ partials, float* __restrict__ out)
{
  const int lane = threadIdx.x;
  float a = 0.f;
  #pragma unroll
  for (int i = 0; i < 16; ++i) a += partials[i * 64 + lane];
  #pragma unroll
  for (int m = 32; m >= 1; m >>= 1) a += __shfl_xor(a, m);
  if (lane == 0) out[0] = a * (float)(1.0 / ((double)T_ * B_ * F_));
}

extern "C" void kernel_launch(void* const* d_in, const int* in_sizes, int n_in,
                              void* d_out, int out_size, void* d_ws, size_t ws_size,
                              hipStream_t stream) {
  const float* feats = (const float*)d_in[0];
  const float* e0    = (const float*)d_in[1];
  const float* W_ih  = (const float*)d_in[2];
  const float* W_hh  = (const float*)d_in[3];
  const float* b_ih  = (const float*)d_in[4];
  const float* b_hh  = (const float*)d_in[5];
  const float* W_dec = (const float*)d_in[6];
  const float* b_dec = (const float*)d_in[7];
  float* out = (float*)d_out;

  float* ws = (float*)d_ws;
  float* h_seq    = ws;                                    // B*T*HS_ floats (b-major, padded)
  float* xgates   = ws + (size_t)B_ * T_ * HS_;            // B*T*G floats (b-major)
  float* partials = xgates + (size_t)T_ * B_ * G_;         // 1024 floats
  float* ehead    = partials + 1024;                       // B*8*H floats (e for t<8)
  float* Wt       = ehead + B_ * P_ * H_;                  // FP_*G_ floats

  hipLaunchKernelGGL(k1a_pool, dim3(T_ * (B_ / 8)), dim3(256), 0, stream,
                     feats, h_seq, W_ih, Wt);
  hipLaunchKernelGGL(k1b_gemm, dim3(B_ * 8), dim3(256), 0, stream,
                     h_seq, Wt, b_ih, xgates);
  hipLaunchKernelGGL(k2_recur, dim3(B_), dim3(64), 0, stream,
                     e0, W_hh, b_hh, xgates, xgates, ehead);
  hipLaunchKernelGGL(k4_decode, dim3((T_ * B_) / K4_ROWS), dim3(256), 0, stream,
                     W_dec, b_dec, h_seq, xgates, ehead, partials);
  hipLaunchKernelGGL(k3_reduce, dim3(1), dim3(64), 0, stream,
                     partials, out);
}